// Round 1
// baseline (366.888 us; speedup 1.0000x reference)
//
#include <hip/hip_runtime.h>

typedef __bf16 bf16x8 __attribute__((ext_vector_type(8)));
typedef float  f32x4  __attribute__((ext_vector_type(4)));

constexpr int BM = 128, BN = 128, BK = 32;
constexpr int MDIM = 65536, NDIM = 1152, KDIM = 768;
constexpr int NBN = NDIM / BN;   // 9
constexpr int NKT = KDIM / BK;   // 24
constexpr int LDSROWB = BK * 2;  // 64 bytes per LDS row (32 bf16)

__device__ __forceinline__ unsigned short f2bf(float f) {
  union { float f; unsigned u; } v; v.f = f;
  return (unsigned short)((v.u + 0x7FFFu + ((v.u >> 16) & 1u)) >> 16);
}

__global__ __launch_bounds__(256, 2)
void siglip_embed_kernel(const float* __restrict__ A,     // [65536, 768] pixel_values
                         const int*   __restrict__ ss,    // [64, 2] spatial_shapes
                         const float* __restrict__ Wm,    // [1152, 768]
                         const float* __restrict__ bias,  // [1152]
                         const float* __restrict__ pos,   // [256, 1152] (16x16 grid)
                         float* __restrict__ out)         // [65536, 1152]
{
  __shared__ unsigned short As[2][BM * BK];
  __shared__ unsigned short Bs[2][BM * BK];

  const int tid  = threadIdx.x;
  const int lane = tid & 63;
  const int wid  = tid >> 6;
  const int wr   = wid >> 1;      // wave row (0..1)
  const int wc   = wid & 1;       // wave col (0..1)

  const int bid = blockIdx.x;
  const int bm  = bid / NBN;
  const int bn  = bid % NBN;

  // ---------------- staging setup (global -> reg -> cvt -> LDS) ----------------
  const int srow0 = tid >> 3;   // 0..31: row within a 32-row round
  const int skc   = tid & 7;    // 0..7: which 16B (4-float) chunk of the 32-k slice
  const float* Ag = A  + (size_t)(bm * BM + srow0) * KDIM + skc * 4;
  const float* Bg = Wm + (size_t)(bn * BN + srow0) * KDIM + skc * 4;

  float4 ra[4], rb[4];

  auto stage_load = [&](int kt) {
    const int ko = kt * BK;
#pragma unroll
    for (int r = 0; r < 4; ++r) {
      ra[r] = *reinterpret_cast<const float4*>(Ag + (size_t)(r * 32) * KDIM + ko);
      rb[r] = *reinterpret_cast<const float4*>(Bg + (size_t)(r * 32) * KDIM + ko);
    }
  };

  auto stage_write = [&](int buf) {
#pragma unroll
    for (int r = 0; r < 4; ++r) {
      const int arow = r * 32 + srow0;
      int off = arow * LDSROWB + skc * 8;
      off ^= (arow & 7) << 4;                       // T2 XOR swizzle
      uint2 pa, pb;
      pa.x = (unsigned)f2bf(ra[r].x) | ((unsigned)f2bf(ra[r].y) << 16);
      pa.y = (unsigned)f2bf(ra[r].z) | ((unsigned)f2bf(ra[r].w) << 16);
      pb.x = (unsigned)f2bf(rb[r].x) | ((unsigned)f2bf(rb[r].y) << 16);
      pb.y = (unsigned)f2bf(rb[r].z) | ((unsigned)f2bf(rb[r].w) << 16);
      *reinterpret_cast<uint2*>(reinterpret_cast<char*>(&As[buf][0]) + off) = pa;
      *reinterpret_cast<uint2*>(reinterpret_cast<char*>(&Bs[buf][0]) + off) = pb;
    }
  };

  // ---------------- MFMA fragments ----------------
  f32x4 acc[4][4];
#pragma unroll
  for (int i = 0; i < 4; ++i)
#pragma unroll
    for (int j = 0; j < 4; ++j)
      acc[i][j] = (f32x4)0.0f;

  const int fr = lane & 15;   // row-in-fragment (A row / B "row" = output col)
  const int kg = lane >> 4;   // k-group 0..3
  // row&7 == fr&7 (wave/fragment offsets are multiples of 8/16), so swizzle mask
  // is lane-constant and offsets stay base+immediate.
  int abase = (wr * 64 + fr) * LDSROWB + kg * 16; abase ^= (fr & 7) << 4;
  int bbase = (wc * 64 + fr) * LDSROWB + kg * 16; bbase ^= (fr & 7) << 4;

  auto compute = [&](int buf) {
    const char* pa = reinterpret_cast<const char*>(&As[buf][0]);
    const char* pb = reinterpret_cast<const char*>(&Bs[buf][0]);
    bf16x8 af[4], bfv[4];
#pragma unroll
    for (int mf = 0; mf < 4; ++mf)
      af[mf] = *reinterpret_cast<const bf16x8*>(pa + abase + mf * 16 * LDSROWB);
#pragma unroll
    for (int nf = 0; nf < 4; ++nf)
      bfv[nf] = *reinterpret_cast<const bf16x8*>(pb + bbase + nf * 16 * LDSROWB);
#pragma unroll
    for (int mf = 0; mf < 4; ++mf)
#pragma unroll
      for (int nf = 0; nf < 4; ++nf)
        acc[mf][nf] = __builtin_amdgcn_mfma_f32_16x16x32_bf16(af[mf], bfv[nf], acc[mf][nf], 0, 0, 0);
  };

  // ---------------- main loop: 1 barrier / K-step, T14 async stage ----------------
  stage_load(0);
  stage_write(0);

  for (int kt = 0; kt < NKT; ++kt) {
    const int cur = kt & 1;
    if (kt + 1 < NKT) stage_load(kt + 1);   // issue loads early: latency hides under MFMA
    __syncthreads();                        // buf[cur] writes visible; buf[cur^1] free
    compute(cur);
    if (kt + 1 < NKT) stage_write(cur ^ 1); // write after compute (other bufs untouched)
  }

  // ---------------- epilogue: bias + bilinear pos-emb + store ----------------
  const int colbase = bn * BN + wc * 64 + fr;
  float bvals[4];
#pragma unroll
  for (int nf = 0; nf < 4; ++nf) bvals[nf] = bias[colbase + nf * 16];

  const int s  = bm >> 3;          // 8 blocks of 128 rows per 1024-row sample
  const int h  = ss[2 * s];
  const int w  = ss[2 * s + 1];
  const int hw = h * w;
  const float rh = 16.0f / (float)h;
  const float rw = 16.0f / (float)w;

  const int row0 = bm * BM + wr * 64 + kg * 4;

#pragma unroll
  for (int mf = 0; mf < 4; ++mf) {
#pragma unroll
    for (int rg = 0; rg < 4; ++rg) {
      const int row = row0 + mf * 16 + rg;
      int p = row & 1023;
      if (p >= hw) p = 0;          // padded region replicates resized[0] == grid[0,0]
      const int y = p / w;
      const int x = p - y * w;
      const float fy = ((float)y + 0.5f) * rh - 0.5f;
      const float fx = ((float)x + 0.5f) * rw - 0.5f;
      const float yf = floorf(fy), xf = floorf(fx);
      const float ty = fy - yf,   tx = fx - xf;
      int iy0 = (int)yf, ix0 = (int)xf;
      int iy1 = iy0 + 1 > 15 ? 15 : iy0 + 1;
      int ix1 = ix0 + 1 > 15 ? 15 : ix0 + 1;
      iy0 = iy0 < 0 ? 0 : iy0;
      ix0 = ix0 < 0 ? 0 : ix0;
      const float* g00 = pos + (size_t)(iy0 * 16 + ix0) * NDIM;
      const float* g01 = pos + (size_t)(iy0 * 16 + ix1) * NDIM;
      const float* g10 = pos + (size_t)(iy1 * 16 + ix0) * NDIM;
      const float* g11 = pos + (size_t)(iy1 * 16 + ix1) * NDIM;
      float* orow = out + (size_t)row * NDIM;
#pragma unroll
      for (int nf = 0; nf < 4; ++nf) {
        const int col = colbase + nf * 16;
        const float p00 = g00[col], p01 = g01[col];
        const float p10 = g10[col], p11 = g11[col];
        const float top = p00 + tx * (p01 - p00);
        const float bot = p10 + tx * (p11 - p10);
        const float pv  = top + ty * (bot - top);
        orow[col] = acc[mf][nf][rg] + bvals[nf] + pv;
      }
    }
  }
}

extern "C" void kernel_launch(void* const* d_in, const int* in_sizes, int n_in,
                              void* d_out, int out_size, void* d_ws, size_t ws_size,
                              hipStream_t stream) {
  const float* A    = (const float*)d_in[0];
  const int*   ss   = (const int*)d_in[1];
  const float* Wm   = (const float*)d_in[2];
  const float* bias = (const float*)d_in[3];
  const float* pos  = (const float*)d_in[4];
  float* out = (float*)d_out;

  const int grid = (MDIM / BM) * NBN;   // 512 * 9 = 4608
  siglip_embed_kernel<<<grid, 256, 0, stream>>>(A, ss, Wm, bias, pos, out);
}

// Round 2
// 292.824 us; speedup vs baseline: 1.2529x; 1.2529x over previous
//
#include <hip/hip_runtime.h>

typedef __bf16 bf16x8 __attribute__((ext_vector_type(8)));
typedef float  f32x4  __attribute__((ext_vector_type(4)));

constexpr int BM = 128, BN = 128, BK = 32;
constexpr int MDIM = 65536, NDIM = 1152, KDIM = 768;
constexpr int NBN = NDIM / BN;          // 9
constexpr int NKT = KDIM / BK;          // 24
constexpr int GRID = (MDIM / BM) * NBN; // 4608 (divisible by 8 -> bijective XCD swizzle)
constexpr int LDSROWB = BK * 2;         // 64 bytes per LDS row (32 bf16)

__device__ __forceinline__ void gload16(const void* g, void* l) {
  __builtin_amdgcn_global_load_lds(
      (const __attribute__((address_space(1))) void*)g,
      (__attribute__((address_space(3))) void*)l, 16, 0, 0);
}

__device__ __forceinline__ unsigned pk2(float x, float y) {
  __bf16 a = (__bf16)x, b = (__bf16)y;   // native cast -> v_cvt_pk_bf16_f32 (RNE)
  return (unsigned)__builtin_bit_cast(unsigned short, a) |
         ((unsigned)__builtin_bit_cast(unsigned short, b) << 16);
}

// ---------------- shared epilogue: bias + bilinear pos-emb + store ----------------
__device__ __forceinline__ void epilogue(const f32x4 acc[4][4], int bm, int bn,
                                         int wr, int wc, int lane,
                                         const int* __restrict__ ss,
                                         const float* __restrict__ bias,
                                         const float* __restrict__ pos,
                                         float* __restrict__ out) {
  const int fr = lane & 15;
  const int kg = lane >> 4;
  const int colbase = bn * BN + wc * 64 + fr;
  float bvals[4];
#pragma unroll
  for (int nf = 0; nf < 4; ++nf) bvals[nf] = bias[colbase + nf * 16];

  const int s  = bm >> 3;          // 8 blocks of 128 rows per 1024-row sample
  const int h  = ss[2 * s];
  const int w  = ss[2 * s + 1];
  const int hw = h * w;
  const float rh = 16.0f / (float)h;
  const float rw = 16.0f / (float)w;

  const int row0 = bm * BM + wr * 64 + kg * 4;

#pragma unroll
  for (int mf = 0; mf < 4; ++mf) {
#pragma unroll
    for (int rg = 0; rg < 4; ++rg) {
      const int row = row0 + mf * 16 + rg;
      int p = row & 1023;
      if (p >= hw) p = 0;          // padded region replicates resized[0] == grid[0,0]
      const int y = p / w;
      const int x = p - y * w;
      const float fy = ((float)y + 0.5f) * rh - 0.5f;
      const float fx = ((float)x + 0.5f) * rw - 0.5f;
      const float yf = floorf(fy), xf = floorf(fx);
      const float ty = fy - yf,   tx = fx - xf;
      int iy0 = (int)yf, ix0 = (int)xf;
      int iy1 = iy0 + 1 > 15 ? 15 : iy0 + 1;
      int ix1 = ix0 + 1 > 15 ? 15 : ix0 + 1;
      iy0 = iy0 < 0 ? 0 : iy0;
      ix0 = ix0 < 0 ? 0 : ix0;
      const float* g00 = pos + (size_t)(iy0 * 16 + ix0) * NDIM;
      const float* g01 = pos + (size_t)(iy0 * 16 + ix1) * NDIM;
      const float* g10 = pos + (size_t)(iy1 * 16 + ix0) * NDIM;
      const float* g11 = pos + (size_t)(iy1 * 16 + ix1) * NDIM;
      float* orow = out + (size_t)row * NDIM;
#pragma unroll
      for (int nf = 0; nf < 4; ++nf) {
        const int col = colbase + nf * 16;
        const float p00 = g00[col], p01 = g01[col];
        const float p10 = g10[col], p11 = g11[col];
        const float top = p00 + tx * (p01 - p00);
        const float bot = p10 + tx * (p11 - p10);
        const float pv  = top + ty * (bot - top);
        orow[col] = acc[mf][nf][rg] + bvals[nf] + pv;
      }
    }
  }
}

// ---------------- fp32 -> bf16 pre-convert (memory-bound) ----------------
__global__ __launch_bounds__(256)
void cvt_bf16_kernel(const float* __restrict__ in, __bf16* __restrict__ out, int n8) {
  int i = blockIdx.x * blockDim.x + threadIdx.x;
  const int stride = gridDim.x * blockDim.x;
  for (; i < n8; i += stride) {
    const float4 a = reinterpret_cast<const float4*>(in)[2 * i];
    const float4 b = reinterpret_cast<const float4*>(in)[2 * i + 1];
    bf16x8 r;
    r[0] = (__bf16)a.x; r[1] = (__bf16)a.y; r[2] = (__bf16)a.z; r[3] = (__bf16)a.w;
    r[4] = (__bf16)b.x; r[5] = (__bf16)b.y; r[6] = (__bf16)b.z; r[7] = (__bf16)b.w;
    reinterpret_cast<bf16x8*>(out)[i] = r;
  }
}

// ---------------- main GEMM, bf16 inputs, global_load_lds staging (m97 structure) ----
__global__ __launch_bounds__(256, 2)
void gemm_pre_kernel(const __bf16* __restrict__ Ab,   // [65536,768] bf16
                     const __bf16* __restrict__ Bb,   // [1152,768] bf16
                     const int*   __restrict__ ss,
                     const float* __restrict__ bias,
                     const float* __restrict__ pos,
                     float* __restrict__ out) {
  __shared__ __bf16 As[2][BM * BK];
  __shared__ __bf16 Bs[2][BM * BK];

  const int tid  = threadIdx.x;
  const int lane = tid & 63;
  const int wid  = tid >> 6;
  const int wr   = wid >> 1;
  const int wc   = wid & 1;

  // XCD-aware bijective swizzle: XCD x runs logical ids [x*576, (x+1)*576)
  const int bidh = blockIdx.x;
  const int bid  = (bidh & 7) * (GRID / 8) + (bidh >> 3);
  const int bm   = bid / NBN;
  const int bn   = bid % NBN;

  const __bf16* Abase = Ab + (size_t)bm * BM * KDIM;
  const __bf16* Bbase = Bb + (size_t)bn * BN * KDIM;

  auto stage = [&](int kt, int buf) {
    const int ko = kt * BK;
#pragma unroll
    for (int i = 0; i < 2; ++i) {
      const int c   = i * 256 + tid;   // chunk 0..511; 16B each; lane-linear in LDS
      const int row = c >> 2;
      const int prt = c & 3;
      gload16(Abase + (size_t)row * KDIM + ko + prt * 8,
              (char*)(&As[buf][0]) + c * 16);
      gload16(Bbase + (size_t)row * KDIM + ko + prt * 8,
              (char*)(&Bs[buf][0]) + c * 16);
    }
  };

  f32x4 acc[4][4];
#pragma unroll
  for (int i = 0; i < 4; ++i)
#pragma unroll
    for (int j = 0; j < 4; ++j) acc[i][j] = (f32x4)0.0f;

  const int fr = lane & 15;
  const int kg = lane >> 4;
  const int abase = (wr * 64 + fr) * LDSROWB + kg * 16;  // linear [128][32]bf16
  const int bbase = (wc * 64 + fr) * LDSROWB + kg * 16;

  auto compute = [&](int buf) {
    const char* pa = reinterpret_cast<const char*>(&As[buf][0]);
    const char* pb = reinterpret_cast<const char*>(&Bs[buf][0]);
    bf16x8 af[4], bfv[4];
#pragma unroll
    for (int mf = 0; mf < 4; ++mf)
      af[mf] = *reinterpret_cast<const bf16x8*>(pa + abase + mf * 16 * LDSROWB);
#pragma unroll
    for (int nf = 0; nf < 4; ++nf)
      bfv[nf] = *reinterpret_cast<const bf16x8*>(pb + bbase + nf * 16 * LDSROWB);
#pragma unroll
    for (int mf = 0; mf < 4; ++mf)
#pragma unroll
      for (int nf = 0; nf < 4; ++nf)
        acc[mf][nf] = __builtin_amdgcn_mfma_f32_16x16x32_bf16(af[mf], bfv[nf], acc[mf][nf], 0, 0, 0);
  };

  stage(0, 0);
  for (int kt = 0; kt < NKT; ++kt) {
    const int cur = kt & 1;
    __syncthreads();                           // drains loads of buf[cur]
    if (kt + 1 < NKT) stage(kt + 1, cur ^ 1);  // prefetch flies under MFMA
    compute(cur);
  }

  epilogue(acc, bm, bn, wr, wc, lane, ss, bias, pos, out);
}

// ---------------- fallback: fp32 inputs, reg-stage + on-the-fly convert ----------------
__global__ __launch_bounds__(256, 2)
void gemm_fb_kernel(const float* __restrict__ A,
                    const int*   __restrict__ ss,
                    const float* __restrict__ Wm,
                    const float* __restrict__ bias,
                    const float* __restrict__ pos,
                    float* __restrict__ out) {
  __shared__ unsigned short As[2][BM * BK];
  __shared__ unsigned short Bs[2][BM * BK];

  const int tid  = threadIdx.x;
  const int lane = tid & 63;
  const int wid  = tid >> 6;
  const int wr   = wid >> 1;
  const int wc   = wid & 1;

  const int bidh = blockIdx.x;
  const int bid  = (bidh & 7) * (GRID / 8) + (bidh >> 3);
  const int bm   = bid / NBN;
  const int bn   = bid % NBN;

  const int srow0 = tid >> 3;
  const int skc   = tid & 7;
  const float* Ag = A  + (size_t)(bm * BM + srow0) * KDIM + skc * 4;
  const float* Bg = Wm + (size_t)(bn * BN + srow0) * KDIM + skc * 4;

  float4 ra[4], rb[4];

  auto stage_load = [&](int kt) {
    const int ko = kt * BK;
#pragma unroll
    for (int r = 0; r < 4; ++r) {
      ra[r] = *reinterpret_cast<const float4*>(Ag + (size_t)(r * 32) * KDIM + ko);
      rb[r] = *reinterpret_cast<const float4*>(Bg + (size_t)(r * 32) * KDIM + ko);
    }
  };

  auto stage_write = [&](int buf) {
#pragma unroll
    for (int r = 0; r < 4; ++r) {
      const int arow = r * 32 + srow0;
      int off = arow * LDSROWB + skc * 8;
      off ^= (arow & 7) << 4;
      uint2 pa, pb;
      pa.x = pk2(ra[r].x, ra[r].y); pa.y = pk2(ra[r].z, ra[r].w);
      pb.x = pk2(rb[r].x, rb[r].y); pb.y = pk2(rb[r].z, rb[r].w);
      *reinterpret_cast<uint2*>(reinterpret_cast<char*>(&As[buf][0]) + off) = pa;
      *reinterpret_cast<uint2*>(reinterpret_cast<char*>(&Bs[buf][0]) + off) = pb;
    }
  };

  f32x4 acc[4][4];
#pragma unroll
  for (int i = 0; i < 4; ++i)
#pragma unroll
    for (int j = 0; j < 4; ++j) acc[i][j] = (f32x4)0.0f;

  const int fr = lane & 15;
  const int kg = lane >> 4;
  int abase = (wr * 64 + fr) * LDSROWB + kg * 16; abase ^= (fr & 7) << 4;
  int bbase = (wc * 64 + fr) * LDSROWB + kg * 16; bbase ^= (fr & 7) << 4;

  auto compute = [&](int buf) {
    const char* pa = reinterpret_cast<const char*>(&As[buf][0]);
    const char* pb = reinterpret_cast<const char*>(&Bs[buf][0]);
    bf16x8 af[4], bfv[4];
#pragma unroll
    for (int mf = 0; mf < 4; ++mf)
      af[mf] = *reinterpret_cast<const bf16x8*>(pa + abase + mf * 16 * LDSROWB);
#pragma unroll
    for (int nf = 0; nf < 4; ++nf)
      bfv[nf] = *reinterpret_cast<const bf16x8*>(pb + bbase + nf * 16 * LDSROWB);
#pragma unroll
    for (int mf = 0; mf < 4; ++mf)
#pragma unroll
      for (int nf = 0; nf < 4; ++nf)
        acc[mf][nf] = __builtin_amdgcn_mfma_f32_16x16x32_bf16(af[mf], bfv[nf], acc[mf][nf], 0, 0, 0);
  };

  stage_load(0);
  stage_write(0);
  for (int kt = 0; kt < NKT; ++kt) {
    const int cur = kt & 1;
    if (kt + 1 < NKT) stage_load(kt + 1);
    __syncthreads();
    compute(cur);
    if (kt + 1 < NKT) stage_write(cur ^ 1);
  }

  epilogue(acc, bm, bn, wr, wc, lane, ss, bias, pos, out);
}

extern "C" void kernel_launch(void* const* d_in, const int* in_sizes, int n_in,
                              void* d_out, int out_size, void* d_ws, size_t ws_size,
                              hipStream_t stream) {
  const float* A    = (const float*)d_in[0];
  const int*   ss   = (const int*)d_in[1];
  const float* Wm   = (const float*)d_in[2];
  const float* bias = (const float*)d_in[3];
  const float* pos  = (const float*)d_in[4];
  float* out = (float*)d_out;

  const size_t needA = (size_t)MDIM * KDIM * 2;  // 100,663,296 B
  const size_t needW = (size_t)NDIM * KDIM * 2;  //   1,769,472 B

  if (ws_size >= needA + needW) {
    __bf16* Ab = (__bf16*)d_ws;
    __bf16* Bb = (__bf16*)((char*)d_ws + needA);
    cvt_bf16_kernel<<<2048, 256, 0, stream>>>(A, Ab, MDIM * KDIM / 8);
    cvt_bf16_kernel<<<432, 256, 0, stream>>>(Wm, Bb, NDIM * KDIM / 8);
    gemm_pre_kernel<<<GRID, 256, 0, stream>>>(Ab, Bb, ss, bias, pos, out);
  } else {
    gemm_fb_kernel<<<GRID, 256, 0, stream>>>(A, ss, Wm, bias, pos, out);
  }
}